// Round 6
// baseline (332.811 us; speedup 1.0000x reference)
//
#include <hip/hip_runtime.h>
#include <hip/hip_bf16.h>
#include <math.h>

#define B_    4
#define S_    4096
#define DD    1024
#define MD    512
#define NTOK  16384
#define CHUNK 32
#define NCH   128

typedef unsigned short u16;
typedef unsigned int u32;
typedef __attribute__((ext_vector_type(8))) short short8;
typedef __attribute__((ext_vector_type(4))) float f32x4;
typedef __attribute__((ext_vector_type(4))) unsigned short us4;

__device__ __forceinline__ float bf2f(u16 u) {
    u32 x = ((u32)u) << 16;
    return __builtin_bit_cast(float, x);
}
__device__ __forceinline__ u16 f2bf(float f) {
    u32 x = __builtin_bit_cast(u32, f);
    u32 lsb = (x >> 16) & 1u;
    x += 0x7fffu + lsb;
    return (u16)(x >> 16);
}
__device__ __forceinline__ float gelu_f(float x) {
    float x3 = x * x * x;
    return 0.5f * x * (1.0f + tanhf(0.7978845608028654f * (x + 0.044715f * x3)));
}
__device__ __forceinline__ float gate_from_ff(const float* ff) {
    return 1.0f - 1.0f / (1.0f + expf(-ff[0]));
}

#define GLDS(gp, lp) __builtin_amdgcn_global_load_lds( \
    (const __attribute__((address_space(1))) void*)(gp), \
    (__attribute__((address_space(3))) void*)(lp), 16, 0, 0)

// swizzled LDS offset (u16 units): row-major [128][64] bf16, 128B rows,
// 16B-chunk XOR'd by (row&7). GLDS source is pre-swizzled to match.
__device__ __forceinline__ int swzoff(int row, int byteInRow) {
    return ((row * 128 + byteInRow) ^ ((row & 7) << 4)) >> 1;
}

// ---------------- bf16 MFMA GEMM, 2-phase dbuf, 128x128 tile, BK=64 ----------------
// C = epi(A[N][K] @ BT[M][K]^T + bias). Plain __syncthreads (drain semantics).
template<int EPI, int HB, int OUTBF>
__global__ __launch_bounds__(256) void gemm_bf16_k(
    const u16* __restrict__ A, const u16* __restrict__ BT,
    const float* __restrict__ bias, void* __restrict__ outp,
    int K, int gx, int OM)
{
    __shared__ __align__(16) u16 Al[2][128 * 64];
    __shared__ __align__(16) u16 Bl[2][128 * 64];
    const int tid = threadIdx.x;
    const int w = tid >> 6, l = tid & 63;

    // XCD-chunked bijective swizzle (nwg % 8 == 0), col-fastest.
    const int nwg = gridDim.x;
    const int cpx = nwg >> 3;
    const int o = blockIdx.x;
    const int swz = (o & 7) * cpx + (o >> 3);
    const int bx = swz % gx, by = swz / gx;

    const int rowBase = by * 128, colBase = bx * 128;
    const int wm = (w >> 1) * 64, wn = (w & 1) * 64;

    // staging: seg = 8 rows x 128B = 1KB per GLDS; wave w stages segs 4w..4w+3
    // of A and of B. Global k pre-swizzled so linear LDS == swizzled layout.
    const int srow = l >> 3;                       // 0..7 within seg
    const int skoff = ((l & 7) ^ (l >> 3)) * 8;    // pre-swizzled k-elem offset
    const u16* Ag[4];
    const u16* Bg[4];
#pragma unroll
    for (int j = 0; j < 4; ++j) {
        const int seg = w * 4 + j;
        Ag[j] = A  + (size_t)(rowBase + seg * 8 + srow) * K + skoff;
        Bg[j] = BT + (size_t)(colBase + seg * 8 + srow) * K + skoff;
    }

    f32x4 acc[4][4];
#pragma unroll
    for (int i = 0; i < 4; ++i)
#pragma unroll
        for (int j = 0; j < 4; ++j) acc[i][j] = (f32x4){0.f, 0.f, 0.f, 0.f};

    const int KT = K >> 6;   // BK=64; KT is even (8 or 16)

#define STAGE(kt, buf) do { \
    const size_t ko = (size_t)(kt) << 6; \
    _Pragma("unroll") \
    for (int j = 0; j < 4; ++j) { \
        GLDS(Ag[j] + ko, &Al[buf][(w * 4 + j) * 512]); \
        GLDS(Bg[j] + ko, &Bl[buf][(w * 4 + j) * 512]); \
    } \
} while (0)

    STAGE(0, 0);
    __syncthreads();

    const int lr = l & 15;
    const int gb = (l >> 4) * 16;    // 16B chunk within 64B k-slice
    int cur = 0;
    for (int kt = 0; kt < KT; ++kt) {
        if (kt + 1 < KT) STAGE(kt + 1, cur ^ 1);
#pragma unroll
        for (int ks = 0; ks < 2; ++ks) {
            short8 af[4], bfr[4];
#pragma unroll
            for (int m = 0; m < 4; ++m)
                af[m] = *(const short8*)&Al[cur][swzoff(wm + m * 16 + lr, ks * 64 + gb)];
#pragma unroll
            for (int n = 0; n < 4; ++n)
                bfr[n] = *(const short8*)&Bl[cur][swzoff(wn + n * 16 + lr, ks * 64 + gb)];
#pragma unroll
            for (int m = 0; m < 4; ++m)
#pragma unroll
                for (int n = 0; n < 4; ++n)
                    acc[m][n] = __builtin_amdgcn_mfma_f32_16x16x32_bf16(af[m], bfr[n], acc[m][n], 0, 0, 0);
        }
        __syncthreads();
        cur ^= 1;
    }
#undef STAGE

    const int g4 = (l >> 4) * 4;
    const int col0 = colBase + wn;

    if (OUTBF) {
        // LDS-staged full-line epilogue (round-4 verified): Al[0] is quiescent
        // after the final __syncthreads (KT even => last tile read from buf 1).
        u16* scr = &Al[0][0] + w * 1024;     // [16][64] u16 per wave
        u16* ob = (u16*)outp;
        const bool odd = l & 1;
        const int lrp = lr & ~1;
#pragma unroll
        for (int m = 0; m < 4; ++m) {
            const int baseRow = rowBase + wm + m * 16;
            float vq[4][4];
#pragma unroll
            for (int n = 0; n < 4; ++n) {
                const float bj = HB ? bias[col0 + n * 16 + lr] : 0.0f;
#pragma unroll
                for (int q = 0; q < 4; ++q) {
                    float vv = acc[m][n][q] + bj;
                    if (EPI == 1) vv = gelu_f(vv);
                    vq[n][q] = vv;
                }
            }
#pragma unroll
            for (int n = 0; n < 4; ++n) {
                float pv[4];
#pragma unroll
                for (int q = 0; q < 4; ++q) pv[q] = __shfl_xor(vq[n][q], 1);
                const int q0 = odd ? 2 : 0;
#pragma unroll
                for (int j = 0; j < 2; ++j) {
                    const int qq = q0 + j;
                    float lo = odd ? pv[qq] : vq[n][qq];
                    float hi = odd ? vq[n][qq] : pv[qq];
                    u32 word = (u32)f2bf(lo) | ((u32)f2bf(hi) << 16);
                    *(u32*)&scr[(g4 + qq) * 64 + n * 16 + lrp] = word;
                }
            }
            asm volatile("s_waitcnt lgkmcnt(0)" ::: "memory");
            __builtin_amdgcn_sched_barrier(0);
            short8 r0 = *(const short8*)&scr[(l >> 3) * 64 + (l & 7) * 8];
            short8 r1 = *(const short8*)&scr[((l >> 3) + 8) * 64 + (l & 7) * 8];
            const size_t gaddr = (size_t)(baseRow + (l >> 3)) * OM + col0 + (l & 7) * 8;
            *(short8*)(ob + gaddr) = r0;
            *(short8*)(ob + gaddr + (size_t)8 * OM) = r1;
            __builtin_amdgcn_sched_barrier(0);
        }
    } else {
#pragma unroll
        for (int n = 0; n < 4; ++n) {
            const int col = col0 + n * 16 + lr;
            const float bj = HB ? bias[col] : 0.0f;
#pragma unroll
            for (int m = 0; m < 4; ++m) {
                const int row0 = rowBase + wm + m * 16 + g4;
#pragma unroll
                for (int q = 0; q < 4; ++q) {
                    float vv = acc[m][n][q] + bj;
                    if (EPI == 1) vv = gelu_f(vv);
                    ((float*)outp)[(size_t)(row0 + q) * OM + col] = vv;
                }
            }
        }
    }
}

// ---------------- f32 -> bf16 bulk convert ----------------
__global__ __launch_bounds__(256) void cvt_bf16_k(const float* __restrict__ in,
                                                  u16* __restrict__ out, int n)
{
    size_t i = ((size_t)blockIdx.x * 256 + threadIdx.x) * 8;
    if (i + 8 > (size_t)n) return;
    float4 a = *(const float4*)(in + i);
    float4 b = *(const float4*)(in + i + 4);
    short8 o;
    o[0] = (short)f2bf(a.x); o[1] = (short)f2bf(a.y);
    o[2] = (short)f2bf(a.z); o[3] = (short)f2bf(a.w);
    o[4] = (short)f2bf(b.x); o[5] = (short)f2bf(b.y);
    o[6] = (short)f2bf(b.z); o[7] = (short)f2bf(b.w);
    *(short8*)(out + i) = o;
}

// ---------------- weight transpose+convert ----------------
__global__ __launch_bounds__(256) void wtrans_k(const float* __restrict__ W,
                                                u16* __restrict__ WT, int K, int M)
{
    __shared__ float t[32][33];
    const int tx = threadIdx.x, ty = threadIdx.y;
    const int m0 = blockIdx.x * 32, k0 = blockIdx.y * 32;
#pragma unroll
    for (int i = 0; i < 4; ++i)
        t[ty + i * 8][tx] = W[(size_t)(k0 + ty + i * 8) * M + m0 + tx];
    __syncthreads();
#pragma unroll
    for (int i = 0; i < 4; ++i)
        WT[(size_t)(m0 + ty + i * 8) * K + k0 + tx] = f2bf(t[tx][ty + i * 8]);
}

__global__ __launch_bounds__(256) void wtrans5_k(
    const float* __restrict__ Wa, const float* __restrict__ Wb,
    const float* __restrict__ Wc, const float* __restrict__ Wd_,
    const float* __restrict__ We,
    u16* __restrict__ Ta, u16* __restrict__ Tb, u16* __restrict__ Tc,
    u16* __restrict__ Td, u16* __restrict__ Te)
{
    __shared__ float t[32][33];
    const float* W; u16* T;
    switch (blockIdx.z) {
        case 0: W = Wa; T = Ta; break;
        case 1: W = Wb; T = Tb; break;
        case 2: W = Wc; T = Tc; break;
        case 3: W = Wd_; T = Td; break;
        default: W = We; T = Te; break;
    }
    const int tx = threadIdx.x, ty = threadIdx.y;
    const int m0 = blockIdx.x * 32, k0 = blockIdx.y * 32;
#pragma unroll
    for (int i = 0; i < 4; ++i)
        t[ty + i * 8][tx] = W[(size_t)(k0 + ty + i * 8) * 512 + m0 + tx];
    __syncthreads();
#pragma unroll
    for (int i = 0; i < 4; ++i)
        T[(size_t)(m0 + ty + i * 8) * 512 + k0 + tx] = f2bf(t[tx][ty + i * 8]);
}

// ---------------- LayerNorm, bf16 in-place, two buffers via blockIdx.y ----------------
__global__ __launch_bounds__(256) void ln2_k(u16* __restrict__ X0, u16* __restrict__ X1,
                                             const float* __restrict__ g0, const float* __restrict__ b0,
                                             const float* __restrict__ g1, const float* __restrict__ b1)
{
    const int row = blockIdx.x, tid = threadIdx.x;
    u16* x = (blockIdx.y ? X1 : X0) + (size_t)row * MD;
    const float* g = blockIdx.y ? g1 : g0;
    const float* b = blockIdx.y ? b1 : b0;
    float v0 = bf2f(x[tid]), v1 = bf2f(x[tid + 256]);
    float s = v0 + v1, q = v0 * v0 + v1 * v1;
#pragma unroll
    for (int off = 32; off > 0; off >>= 1) {
        s += __shfl_down(s, off);
        q += __shfl_down(q, off);
    }
    __shared__ float redS[4], redQ[4];
    __shared__ float s_mean, s_rstd;
    const int lane = tid & 63, w = tid >> 6;
    if (lane == 0) { redS[w] = s; redQ[w] = q; }
    __syncthreads();
    if (tid == 0) {
        float S = redS[0] + redS[1] + redS[2] + redS[3];
        float Q = redQ[0] + redQ[1] + redQ[2] + redQ[3];
        float m = S * (1.f / 512.f);
        float var = Q * (1.f / 512.f) - m * m;
        s_mean = m; s_rstd = rsqrtf(var + 1e-5f);
    }
    __syncthreads();
    const float m = s_mean, rs = s_rstd;
    x[tid]       = f2bf((v0 - m) * rs * g[tid]       + b[tid]);
    x[tid + 256] = f2bf((v1 - m) * rs * g[tid + 256] + b[tid + 256]);
}

// ---------------- surprise coefficient ----------------
__global__ __launch_bounds__(256) void surprise_k(const u16* __restrict__ pred,
                                                  const u16* __restrict__ v,
                                                  const float* __restrict__ lr_p,
                                                  float* __restrict__ coef)
{
    const int row = blockIdx.x, tid = threadIdx.x;
    const u16* pp = pred + (size_t)row * MD;
    const u16* vp = v + (size_t)row * MD;
    float d0 = bf2f(pp[tid]) - bf2f(vp[tid]);
    float d1 = bf2f(pp[tid + 256]) - bf2f(vp[tid + 256]);
    float q = d0 * d0 + d1 * d1;
#pragma unroll
    for (int off = 32; off > 0; off >>= 1) q += __shfl_down(q, off);
    __shared__ float redQ[4];
    const int lane = tid & 63, w = tid >> 6;
    if (lane == 0) redQ[w] = q;
    __syncthreads();
    if (tid == 0) {
        float Q = redQ[0] + redQ[1] + redQ[2] + redQ[3];
        coef[row] = lr_p[0] * (Q * (1.f / 512.f));
    }
}

// ---------------- chunked linear scan, vec4 over d ----------------
__global__ __launch_bounds__(256) void scan1_k(u16* __restrict__ io,
                                               const float* __restrict__ coef,
                                               const float* __restrict__ ff,
                                               float* __restrict__ carry)
{
    const int idx = blockIdx.x * blockDim.x + threadIdx.x;  // B*NCH*(MD/4)
    const int d4 = (idx & 127) * 4;
    const int c = (idx >> 7) & (NCH - 1);
    const int b = idx >> 14;
    const float g = gate_from_ff(ff);
    const int tok0 = b * S_ + c * CHUNK;
    u16* p = io + (size_t)tok0 * MD + d4;
    const float* cf = coef + tok0;
    float s0 = 0.f, s1 = 0.f, s2 = 0.f, s3 = 0.f;
#pragma unroll 4
    for (int t = 0; t < CHUNK; ++t) {
        us4 vv = *(const us4*)(p + (size_t)t * MD);
        const float ct = cf[t];
        s0 = fmaf(g, s0, ct * bf2f(vv.x));
        s1 = fmaf(g, s1, ct * bf2f(vv.y));
        s2 = fmaf(g, s2, ct * bf2f(vv.z));
        s3 = fmaf(g, s3, ct * bf2f(vv.w));
        us4 ov = { f2bf(s0), f2bf(s1), f2bf(s2), f2bf(s3) };
        *(us4*)(p + (size_t)t * MD) = ov;
    }
    float4 cw = { s0, s1, s2, s3 };
    *(float4*)(carry + ((size_t)b * NCH + c) * MD + d4) = cw;
}

__global__ __launch_bounds__(256) void scan2_k(const float* __restrict__ carry,
                                               const float* __restrict__ ff,
                                               float* __restrict__ Sin)
{
    const int idx = blockIdx.x * blockDim.x + threadIdx.x;  // B*MD
    const int d = idx & (MD - 1);
    const int b = idx >> 9;
    const float g = gate_from_ff(ff);
    const float gL = powf(g, (float)CHUNK);
    float p = 0.f;
    for (int c = 0; c < NCH; ++c) {
        Sin[((size_t)b * NCH + c) * MD + d] = p;
        p = carry[((size_t)b * NCH + c) * MD + d] + gL * p;
    }
}

// fin = bf16( loc + g^(tl+1)*Sin + retrieved ), vec4
__global__ __launch_bounds__(256) void scan3_k(const u16* __restrict__ loc,
                                               const float* __restrict__ Sin,
                                               const u16* __restrict__ retr,
                                               const float* __restrict__ ff,
                                               u16* __restrict__ fin)
{
    const size_t idx = (size_t)blockIdx.x * blockDim.x + threadIdx.x;  // NTOK*MD/4
    const int d4 = (int)(idx & 127) * 4;
    const int t = (int)((idx >> 7) & (S_ - 1));
    const int b = (int)(idx >> 19);
    const int c = t >> 5, tl = t & (CHUNK - 1);
    const float g = gate_from_ff(ff);
    const float f = exp2f((float)(tl + 1) * log2f(g));
    const size_t row = (size_t)(b * S_ + t) * MD + d4;
    us4 lv = *(const us4*)(loc + row);
    us4 rv = *(const us4*)(retr + row);
    float4 sv = *(const float4*)(Sin + ((size_t)b * NCH + c) * MD + d4);
    us4 ov;
    ov.x = f2bf(bf2f(lv.x) + f * sv.x + bf2f(rv.x));
    ov.y = f2bf(bf2f(lv.y) + f * sv.y + bf2f(rv.y));
    ov.z = f2bf(bf2f(lv.z) + f * sv.z + bf2f(rv.z));
    ov.w = f2bf(bf2f(lv.w) + f * sv.w + bf2f(rv.w));
    *(us4*)(fin + row) = ov;
}

extern "C" void kernel_launch(void* const* d_in, const int* in_sizes, int n_in,
                              void* d_out, int out_size, void* d_ws, size_t ws_size,
                              hipStream_t stream) {
    const float* x   = (const float*)d_in[0];
    const float* Wd  = (const float*)d_in[1];
    const float* bd  = (const float*)d_in[2];
    const float* Wu  = (const float*)d_in[3];
    const float* bu  = (const float*)d_in[4];
    const float* Wq  = (const float*)d_in[5];
    const float* bq  = (const float*)d_in[6];
    const float* Wk  = (const float*)d_in[7];
    const float* bk  = (const float*)d_in[8];
    const float* Wv  = (const float*)d_in[9];
    const float* bv  = (const float*)d_in[10];
    const float* qg  = (const float*)d_in[11];
    const float* qb  = (const float*)d_in[12];
    const float* kg  = (const float*)d_in[13];
    const float* kb  = (const float*)d_in[14];
    const float* W0  = (const float*)d_in[15];
    const float* W1  = (const float*)d_in[16];
    const float* lr  = (const float*)d_in[17];
    const float* ff  = (const float*)d_in[18];
    float* out = (float*)d_out;

    // ---- workspace layout ----
    u16* wdT   = (u16*)d_ws;                     // [512][1024]
    u16* wqT   = wdT + 512 * 1024;               // [512][512]
    u16* wkT   = wqT + 512 * 512;
    u16* wvT   = wkT + 512 * 512;
    u16* w0T   = wvT + 512 * 512;
    u16* w1T   = w0T + 512 * 512;
    u16* wuT   = w1T + 512 * 512;                // [1024][512]
    u16* xb    = wuT + 1024 * 512;               // [16384][1024] bf16
    u16* hb    = xb + (size_t)NTOK * DD;         // [16384][512] h
    u16* b1    = hb + (size_t)NTOK * MD;         // qpre/q -> retrieved
    u16* b2    = b1 + (size_t)NTOK * MD;         // kpre/k -> pred
    u16* VB    = b2 + (size_t)NTOK * MD;         // v -> scan-local
    u16* ax    = VB + (size_t)NTOK * MD;         // aq -> ak -> fin
    float* coef  = (float*)(ax + (size_t)NTOK * MD);   // [16384]
    float* carry = coef + NTOK;                  // [B][NCH][MD]
    float* Sin   = carry + (size_t)B_ * NCH * MD;

    dim3 blk(256);
    dim3 t32(32, 8);

    cvt_bf16_k<<<(NTOK * DD) / (256 * 8), blk, 0, stream>>>(x, xb, NTOK * DD);
    wtrans_k<<<dim3(16, 32), t32, 0, stream>>>(Wd, wdT, 1024, 512);
    wtrans5_k<<<dim3(16, 16, 5), t32, 0, stream>>>(Wq, Wk, Wv, W0, W1,
        wqT, wkT, wvT, w0T, w1T);
    wtrans_k<<<dim3(32, 16), t32, 0, stream>>>(Wu, wuT, 512, 1024);

    // G1: h = x @ Wd + bd -> hb. grid 4x128 = 512, K=1024
    gemm_bf16_k<0, 1, 1><<<dim3(512), blk, 0, stream>>>(xb, wdT, bd, hb, 1024, 4, 512);
    // G2/G3/G4: qpre/kpre/v (split 512-block launches, K=512)
    gemm_bf16_k<0, 1, 1><<<dim3(512), blk, 0, stream>>>(hb, wqT, bq, b1, 512, 4, 512);
    gemm_bf16_k<0, 1, 1><<<dim3(512), blk, 0, stream>>>(hb, wkT, bk, b2, 512, 4, 512);
    gemm_bf16_k<0, 1, 1><<<dim3(512), blk, 0, stream>>>(hb, wvT, bv, VB, 512, 4, 512);
    // LN in-place on b1,b2
    ln2_k<<<dim3(NTOK, 2), blk, 0, stream>>>(b1, b2, qg, qb, kg, kb);
    // G5: aq = gelu(q @ W0) -> ax
    gemm_bf16_k<1, 0, 1><<<dim3(512), blk, 0, stream>>>(b1, w0T, nullptr, ax, 512, 4, 512);
    // G6: retrieved = aq @ W1 -> b1
    gemm_bf16_k<0, 0, 1><<<dim3(512), blk, 0, stream>>>(ax, w1T, nullptr, b1, 512, 4, 512);
    // G7: ak = gelu(k @ W0) -> ax
    gemm_bf16_k<1, 0, 1><<<dim3(512), blk, 0, stream>>>(b2, w0T, nullptr, ax, 512, 4, 512);
    // G8: pred = ak @ W1 -> b2
    gemm_bf16_k<0, 0, 1><<<dim3(512), blk, 0, stream>>>(ax, w1T, nullptr, b2, 512, 4, 512);
    // surprise coefficient per token
    surprise_k<<<NTOK, blk, 0, stream>>>(b2, VB, lr, coef);
    // chunked scan over inputs = coef * v (VB in-place -> scan local)
    scan1_k<<<(B_ * NCH * (MD / 4)) / 256, blk, 0, stream>>>(VB, coef, ff, carry);
    scan2_k<<<(B_ * MD) / 256, blk, 0, stream>>>(carry, ff, Sin);
    // fin = loc + g^..*Sin + retrieved -> ax
    scan3_k<<<(NTOK * (MD / 4)) / 256, blk, 0, stream>>>(VB, Sin, b1, ff, ax);
    // G9: out = fin @ Wu + bu (f32 out). grid 8x128 = 1024
    gemm_bf16_k<0, 1, 0><<<dim3(1024), blk, 0, stream>>>(ax, wuT, bu, out, 512, 8, 1024);
}

// Round 7
// 329.578 us; speedup vs baseline: 1.0098x; 1.0098x over previous
//
#include <hip/hip_runtime.h>
#include <hip/hip_bf16.h>
#include <math.h>

#define B_    4
#define S_    4096
#define DD    1024
#define MD    512
#define NTOK  16384
#define CHUNK 32
#define NCH   128

typedef unsigned short u16;
typedef unsigned int u32;
typedef __attribute__((ext_vector_type(8))) short short8;
typedef __attribute__((ext_vector_type(4))) float f32x4;
typedef __attribute__((ext_vector_type(4))) unsigned short us4;

__device__ __forceinline__ float bf2f(u16 u) {
    u32 x = ((u32)u) << 16;
    return __builtin_bit_cast(float, x);
}
__device__ __forceinline__ u16 f2bf(float f) {
    u32 x = __builtin_bit_cast(u32, f);
    u32 lsb = (x >> 16) & 1u;
    x += 0x7fffu + lsb;
    return (u16)(x >> 16);
}
__device__ __forceinline__ float gelu_f(float x) {
    float x3 = x * x * x;
    return 0.5f * x * (1.0f + tanhf(0.7978845608028654f * (x + 0.044715f * x3)));
}
__device__ __forceinline__ float gate_from_ff(const float* ff) {
    return 1.0f - 1.0f / (1.0f + expf(-ff[0]));
}

#define GLDS(gp, lp) __builtin_amdgcn_global_load_lds( \
    (const __attribute__((address_space(1))) void*)(gp), \
    (__attribute__((address_space(3))) void*)(lp), 16, 0, 0)

// ---------------- bf16 MFMA GEMM: 3-buffer, depth-2 counted-vmcnt pipeline ----
// 128x128 tile, BK=32, 4 waves. z-slice selects an independent {A,W,bias,out}.
// LDS rows are 64B; 16B chunks XOR-swizzled by (row&3); GLDS source pre-swizzled.
template<int EPI, int HB, int OUTBF>
__global__ __launch_bounds__(256) void gemm_bf16_k(
    const u16* __restrict__ A0, const u16* __restrict__ A1, const u16* __restrict__ A2,
    const u16* __restrict__ W0p, const u16* __restrict__ W1p, const u16* __restrict__ W2p,
    const float* __restrict__ c0, const float* __restrict__ c1, const float* __restrict__ c2,
    void* __restrict__ o0, void* __restrict__ o1, void* __restrict__ o2,
    int K, int gx, int OM)
{
    __shared__ __align__(16) u16 Al[3][128 * 32];
    __shared__ __align__(16) u16 Bl[3][128 * 32];
    const int tid = threadIdx.x;
    const int w = tid >> 6, l = tid & 63;

    const int z = blockIdx.z;
    const u16* A      = (z == 0) ? A0 : (z == 1) ? A1 : A2;
    const u16* BT     = (z == 0) ? W0p : (z == 1) ? W1p : W2p;
    const float* bias = (z == 0) ? c0 : (z == 1) ? c1 : c2;
    void* outp        = (z == 0) ? o0 : (z == 1) ? o1 : o2;

    // XCD-chunked bijective swizzle within the z-slice (gridDim.x % 8 == 0).
    const int nwg = gridDim.x;
    const int cpx = nwg >> 3;
    const int o = blockIdx.x;
    const int swz = (o & 7) * cpx + (o >> 3);
    const int bx = swz % gx, by = swz / gx;

    const int rowBase = by * 128, colBase = bx * 128;
    const int wm = (w >> 1) * 64, wn = (w & 1) * 64;
    const int lr = l & 15;

    // ---- bias preload BEFORE any staging: keeps the counted-vmcnt window pure
    float bj[4] = {0.f, 0.f, 0.f, 0.f};
    if (HB) {
#pragma unroll
        for (int n = 0; n < 4; ++n) bj[n] = bias[colBase + wn + n * 16 + lr];
        asm volatile("" :: "v"(bj[0]), "v"(bj[1]), "v"(bj[2]), "v"(bj[3]));
    }
    asm volatile("s_waitcnt vmcnt(0)" ::: "memory");
    __builtin_amdgcn_sched_barrier(0);

    // staging (BK=32): seg = 16 rows x 64B = 1KB per GLDS; wave w covers
    // segs {w, w+4} of A and of B. Global 16B-chunk pre-swizzled by row&3.
    const int srow = l >> 2;                         // 0..15
    const int skoff = ((l & 3) ^ (srow & 3)) * 8;    // pre-swizzled chunk, elems
    const u16* Ag0 = A  + (size_t)(rowBase + w * 16 + srow) * K + skoff;
    const u16* Ag1 = A  + (size_t)(rowBase + (w + 4) * 16 + srow) * K + skoff;
    const u16* Bg0 = BT + (size_t)(colBase + w * 16 + srow) * K + skoff;
    const u16* Bg1 = BT + (size_t)(colBase + (w + 4) * 16 + srow) * K + skoff;

    f32x4 acc[4][4];
#pragma unroll
    for (int i = 0; i < 4; ++i)
#pragma unroll
        for (int j = 0; j < 4; ++j) acc[i][j] = (f32x4){0.f, 0.f, 0.f, 0.f};

    const int KT = K >> 5;

#define STAGE(kt, buf) do { \
    const size_t ko = (size_t)(kt) << 5; \
    GLDS(Ag0 + ko, &Al[buf][(w * 16) * 32]); \
    GLDS(Ag1 + ko, &Al[buf][((w + 4) * 16) * 32]); \
    GLDS(Bg0 + ko, &Bl[buf][(w * 16) * 32]); \
    GLDS(Bg1 + ko, &Bl[buf][((w + 4) * 16) * 32]); \
} while (0)

    // prologue: stage tiles 0,1; wait only tile 0's 4 loads (4 remain in flight)
    STAGE(0, 0);
    STAGE(1, 1);
    asm volatile("s_waitcnt vmcnt(4)" ::: "memory");
    __builtin_amdgcn_sched_barrier(0);
    __builtin_amdgcn_s_barrier();
    __builtin_amdgcn_sched_barrier(0);

    // read-side swizzle: row = ..+lr, chunk = l>>4; (chunk ^ (row&3)) with
    // row&3 == l&3  =>  per-lane constant offset.
    const int rsw = (((l >> 4) ^ (l & 3)) << 3);
    int bt = 0;
    for (int t = 0; t < KT; ++t) {
        int bs = bt + 2; if (bs >= 3) bs -= 3;
        const bool more = (t + 2) < KT;
        if (more) STAGE(t + 2, bs);
        short8 af[4], bfr[4];
#pragma unroll
        for (int m = 0; m < 4; ++m)
            af[m] = *(const short8*)&Al[bt][(wm + m * 16 + lr) * 32 + rsw];
#pragma unroll
        for (int n = 0; n < 4; ++n)
            bfr[n] = *(const short8*)&Bl[bt][(wn + n * 16 + lr) * 32 + rsw];
#pragma unroll
        for (int m = 0; m < 4; ++m)
#pragma unroll
            for (int n = 0; n < 4; ++n)
                acc[m][n] = __builtin_amdgcn_mfma_f32_16x16x32_bf16(af[m], bfr[n], acc[m][n], 0, 0, 0);
        // counted wait: next tile's loads landed; prefetched tile may stay in flight
        if (more) { asm volatile("s_waitcnt vmcnt(4)" ::: "memory"); }
        else      { asm volatile("s_waitcnt vmcnt(0)" ::: "memory"); }
        __builtin_amdgcn_sched_barrier(0);
        __builtin_amdgcn_s_barrier();
        __builtin_amdgcn_sched_barrier(0);
        bt = (bt + 1 == 3) ? 0 : bt + 1;
    }
#undef STAGE

    const int g4 = (l >> 4) * 4;
    const int col0 = colBase + wn;

    if (OUTBF) {
        // verified LDS-staged full-line bf16 epilogue (rounds 4/6).
        // After the final barrier all LDS reads are done; Al[0] is free.
        u16* scr = &Al[0][0] + w * 1024;     // [16][64] u16 per wave
        u16* ob = (u16*)outp;
        const bool odd = l & 1;
        const int lrp = lr & ~1;
#pragma unroll
        for (int m = 0; m < 4; ++m) {
            const int baseRow = rowBase + wm + m * 16;
            float vq[4][4];
#pragma unroll
            for (int n = 0; n < 4; ++n) {
#pragma unroll
                for (int q = 0; q < 4; ++q) {
                    float vv = acc[m][n][q] + bj[n];
                    if (EPI == 1) vv = gelu_f(vv);
                    vq[n][q] = vv;
                }
            }
#pragma unroll
            for (int n = 0; n < 4; ++n) {
                float pv[4];
#pragma unroll
                for (int q = 0; q < 4; ++q) pv[q] = __shfl_xor(vq[n][q], 1);
                const int q0 = odd ? 2 : 0;
#pragma unroll
                for (int j = 0; j < 2; ++j) {
                    const int qq = q0 + j;
                    float lo = odd ? pv[qq] : vq[n][qq];
                    float hi = odd ? vq[n][qq] : pv[qq];
                    u32 word = (u32)f2bf(lo) | ((u32)f2bf(hi) << 16);
                    *(u32*)&scr[(g4 + qq) * 64 + n * 16 + lrp] = word;
                }
            }
            asm volatile("s_waitcnt lgkmcnt(0)" ::: "memory");
            __builtin_amdgcn_sched_barrier(0);
            short8 r0 = *(const short8*)&scr[(l >> 3) * 64 + (l & 7) * 8];
            short8 r1 = *(const short8*)&scr[((l >> 3) + 8) * 64 + (l & 7) * 8];
            const size_t gaddr = (size_t)(baseRow + (l >> 3)) * OM + col0 + (l & 7) * 8;
            *(short8*)(ob + gaddr) = r0;
            *(short8*)(ob + gaddr + (size_t)8 * OM) = r1;
            __builtin_amdgcn_sched_barrier(0);
        }
    } else {
        // direct f32 stores (round-6 verified)
#pragma unroll
        for (int n = 0; n < 4; ++n) {
            const int col = col0 + n * 16 + lr;
#pragma unroll
            for (int m = 0; m < 4; ++m) {
                const int row0 = rowBase + wm + m * 16 + g4;
#pragma unroll
                for (int q = 0; q < 4; ++q) {
                    float vv = acc[m][n][q] + bj[n];
                    if (EPI == 1) vv = gelu_f(vv);
                    ((float*)outp)[(size_t)(row0 + q) * OM + col] = vv;
                }
            }
        }
    }
}

// ---------------- f32 -> bf16 bulk convert ----------------
__global__ __launch_bounds__(256) void cvt_bf16_k(const float* __restrict__ in,
                                                  u16* __restrict__ out, int n)
{
    size_t i = ((size_t)blockIdx.x * 256 + threadIdx.x) * 8;
    if (i + 8 > (size_t)n) return;
    float4 a = *(const float4*)(in + i);
    float4 b = *(const float4*)(in + i + 4);
    short8 o;
    o[0] = (short)f2bf(a.x); o[1] = (short)f2bf(a.y);
    o[2] = (short)f2bf(a.z); o[3] = (short)f2bf(a.w);
    o[4] = (short)f2bf(b.x); o[5] = (short)f2bf(b.y);
    o[6] = (short)f2bf(b.z); o[7] = (short)f2bf(b.w);
    *(short8*)(out + i) = o;
}

// ---------------- weight transpose+convert ----------------
__global__ __launch_bounds__(256) void wtrans_k(const float* __restrict__ W,
                                                u16* __restrict__ WT, int K, int M)
{
    __shared__ float t[32][33];
    const int tx = threadIdx.x, ty = threadIdx.y;
    const int m0 = blockIdx.x * 32, k0 = blockIdx.y * 32;
#pragma unroll
    for (int i = 0; i < 4; ++i)
        t[ty + i * 8][tx] = W[(size_t)(k0 + ty + i * 8) * M + m0 + tx];
    __syncthreads();
#pragma unroll
    for (int i = 0; i < 4; ++i)
        WT[(size_t)(m0 + ty + i * 8) * K + k0 + tx] = f2bf(t[tx][ty + i * 8]);
}

__global__ __launch_bounds__(256) void wtrans5_k(
    const float* __restrict__ Wa, const float* __restrict__ Wb,
    const float* __restrict__ Wc, const float* __restrict__ Wd_,
    const float* __restrict__ We,
    u16* __restrict__ Ta, u16* __restrict__ Tb, u16* __restrict__ Tc,
    u16* __restrict__ Td, u16* __restrict__ Te)
{
    __shared__ float t[32][33];
    const float* W; u16* T;
    switch (blockIdx.z) {
        case 0: W = Wa; T = Ta; break;
        case 1: W = Wb; T = Tb; break;
        case 2: W = Wc; T = Tc; break;
        case 3: W = Wd_; T = Td; break;
        default: W = We; T = Te; break;
    }
    const int tx = threadIdx.x, ty = threadIdx.y;
    const int m0 = blockIdx.x * 32, k0 = blockIdx.y * 32;
#pragma unroll
    for (int i = 0; i < 4; ++i)
        t[ty + i * 8][tx] = W[(size_t)(k0 + ty + i * 8) * 512 + m0 + tx];
    __syncthreads();
#pragma unroll
    for (int i = 0; i < 4; ++i)
        T[(size_t)(m0 + ty + i * 8) * 512 + k0 + tx] = f2bf(t[tx][ty + i * 8]);
}

// ---------------- LayerNorm, bf16 in-place, two buffers via blockIdx.y ----------------
__global__ __launch_bounds__(256) void ln2_k(u16* __restrict__ X0, u16* __restrict__ X1,
                                             const float* __restrict__ g0, const float* __restrict__ b0,
                                             const float* __restrict__ g1, const float* __restrict__ b1)
{
    const int row = blockIdx.x, tid = threadIdx.x;
    u16* x = (blockIdx.y ? X1 : X0) + (size_t)row * MD;
    const float* g = blockIdx.y ? g1 : g0;
    const float* b = blockIdx.y ? b1 : b0;
    float v0 = bf2f(x[tid]), v1 = bf2f(x[tid + 256]);
    float s = v0 + v1, q = v0 * v0 + v1 * v1;
#pragma unroll
    for (int off = 32; off > 0; off >>= 1) {
        s += __shfl_down(s, off);
        q += __shfl_down(q, off);
    }
    __shared__ float redS[4], redQ[4];
    __shared__ float s_mean, s_rstd;
    const int lane = tid & 63, w = tid >> 6;
    if (lane == 0) { redS[w] = s; redQ[w] = q; }
    __syncthreads();
    if (tid == 0) {
        float S = redS[0] + redS[1] + redS[2] + redS[3];
        float Q = redQ[0] + redQ[1] + redQ[2] + redQ[3];
        float m = S * (1.f / 512.f);
        float var = Q * (1.f / 512.f) - m * m;
        s_mean = m; s_rstd = rsqrtf(var + 1e-5f);
    }
    __syncthreads();
    const float m = s_mean, rs = s_rstd;
    x[tid]       = f2bf((v0 - m) * rs * g[tid]       + b[tid]);
    x[tid + 256] = f2bf((v1 - m) * rs * g[tid + 256] + b[tid + 256]);
}

// ---------------- surprise coefficient ----------------
__global__ __launch_bounds__(256) void surprise_k(const u16* __restrict__ pred,
                                                  const u16* __restrict__ v,
                                                  const float* __restrict__ lr_p,
                                                  float* __restrict__ coef)
{
    const int row = blockIdx.x, tid = threadIdx.x;
    const u16* pp = pred + (size_t)row * MD;
    const u16* vp = v + (size_t)row * MD;
    float d0 = bf2f(pp[tid]) - bf2f(vp[tid]);
    float d1 = bf2f(pp[tid + 256]) - bf2f(vp[tid + 256]);
    float q = d0 * d0 + d1 * d1;
#pragma unroll
    for (int off = 32; off > 0; off >>= 1) q += __shfl_down(q, off);
    __shared__ float redQ[4];
    const int lane = tid & 63, w = tid >> 6;
    if (lane == 0) redQ[w] = q;
    __syncthreads();
    if (tid == 0) {
        float Q = redQ[0] + redQ[1] + redQ[2] + redQ[3];
        coef[row] = lr_p[0] * (Q * (1.f / 512.f));
    }
}

// ---------------- chunked linear scan, vec4 over d ----------------
__global__ __launch_bounds__(256) void scan1_k(u16* __restrict__ io,
                                               const float* __restrict__ coef,
                                               const float* __restrict__ ff,
                                               float* __restrict__ carry)
{
    const int idx = blockIdx.x * blockDim.x + threadIdx.x;  // B*NCH*(MD/4)
    const int d4 = (idx & 127) * 4;
    const int c = (idx >> 7) & (NCH - 1);
    const int b = idx >> 14;
    const float g = gate_from_ff(ff);
    const int tok0 = b * S_ + c * CHUNK;
    u16* p = io + (size_t)tok0 * MD + d4;
    const float* cf = coef + tok0;
    float s0 = 0.f, s1 = 0.f, s2 = 0.f, s3 = 0.f;
#pragma unroll 4
    for (int t = 0; t < CHUNK; ++t) {
        us4 vv = *(const us4*)(p + (size_t)t * MD);
        const float ct = cf[t];
        s0 = fmaf(g, s0, ct * bf2f(vv.x));
        s1 = fmaf(g, s1, ct * bf2f(vv.y));
        s2 = fmaf(g, s2, ct * bf2f(vv.z));
        s3 = fmaf(g, s3, ct * bf2f(vv.w));
        us4 ov = { f2bf(s0), f2bf(s1), f2bf(s2), f2bf(s3) };
        *(us4*)(p + (size_t)t * MD) = ov;
    }
    float4 cw = { s0, s1, s2, s3 };
    *(float4*)(carry + ((size_t)b * NCH + c) * MD + d4) = cw;
}

__global__ __launch_bounds__(256) void scan2_k(const float* __restrict__ carry,
                                               const float* __restrict__ ff,
                                               float* __restrict__ Sin)
{
    const int idx = blockIdx.x * blockDim.x + threadIdx.x;  // B*MD
    const int d = idx & (MD - 1);
    const int b = idx >> 9;
    const float g = gate_from_ff(ff);
    const float gL = powf(g, (float)CHUNK);
    float p = 0.f;
    for (int c = 0; c < NCH; ++c) {
        Sin[((size_t)b * NCH + c) * MD + d] = p;
        p = carry[((size_t)b * NCH + c) * MD + d] + gL * p;
    }
}

// fin = bf16( loc + g^(tl+1)*Sin + retrieved ), vec4
__global__ __launch_bounds__(256) void scan3_k(const u16* __restrict__ loc,
                                               const float* __restrict__ Sin,
                                               const u16* __restrict__ retr,
                                               const float* __restrict__ ff,
                                               u16* __restrict__ fin)
{
    const size_t idx = (size_t)blockIdx.x * blockDim.x + threadIdx.x;  // NTOK*MD/4
    const int d4 = (int)(idx & 127) * 4;
    const int t = (int)((idx >> 7) & (S_ - 1));
    const int b = (int)(idx >> 19);
    const int c = t >> 5, tl = t & (CHUNK - 1);
    const float g = gate_from_ff(ff);
    const float f = exp2f((float)(tl + 1) * log2f(g));
    const size_t row = (size_t)(b * S_ + t) * MD + d4;
    us4 lv = *(const us4*)(loc + row);
    us4 rv = *(const us4*)(retr + row);
    float4 sv = *(const float4*)(Sin + ((size_t)b * NCH + c) * MD + d4);
    us4 ov;
    ov.x = f2bf(bf2f(lv.x) + f * sv.x + bf2f(rv.x));
    ov.y = f2bf(bf2f(lv.y) + f * sv.y + bf2f(rv.y));
    ov.z = f2bf(bf2f(lv.z) + f * sv.z + bf2f(rv.z));
    ov.w = f2bf(bf2f(lv.w) + f * sv.w + bf2f(rv.w));
    *(us4*)(fin + row) = ov;
}

extern "C" void kernel_launch(void* const* d_in, const int* in_sizes, int n_in,
                              void* d_out, int out_size, void* d_ws, size_t ws_size,
                              hipStream_t stream) {
    const float* x   = (const float*)d_in[0];
    const float* Wd  = (const float*)d_in[1];
    const float* bd  = (const float*)d_in[2];
    const float* Wu  = (const float*)d_in[3];
    const float* bu  = (const float*)d_in[4];
    const float* Wq  = (const float*)d_in[5];
    const float* bq  = (const float*)d_in[6];
    const float* Wk  = (const float*)d_in[7];
    const float* bk  = (const float*)d_in[8];
    const float* Wv  = (const float*)d_in[9];
    const float* bv  = (const float*)d_in[10];
    const float* qg  = (const float*)d_in[11];
    const float* qb  = (const float*)d_in[12];
    const float* kg  = (const float*)d_in[13];
    const float* kb  = (const float*)d_in[14];
    const float* W0  = (const float*)d_in[15];
    const float* W1  = (const float*)d_in[16];
    const float* lr  = (const float*)d_in[17];
    const float* ff  = (const float*)d_in[18];
    float* out = (float*)d_out;

    // ---- workspace layout ----
    u16* wdT   = (u16*)d_ws;                     // [512][1024]
    u16* wqT   = wdT + 512 * 1024;               // [512][512]
    u16* wkT   = wqT + 512 * 512;
    u16* wvT   = wkT + 512 * 512;
    u16* w0T   = wvT + 512 * 512;
    u16* w1T   = w0T + 512 * 512;
    u16* wuT   = w1T + 512 * 512;                // [1024][512]
    u16* xb    = wuT + 1024 * 512;               // [16384][1024]; later aq|ak
    u16* hb    = xb + (size_t)NTOK * DD;         // h; later fin
    u16* b1    = hb + (size_t)NTOK * MD;         // qpre/q -> retrieved
    u16* b2    = b1 + (size_t)NTOK * MD;         // kpre/k -> pred
    u16* VB    = b2 + (size_t)NTOK * MD;         // v -> scan-local
    float* coef  = (float*)(VB + (size_t)NTOK * MD);   // [16384]
    float* carry = coef + NTOK;                  // [B][NCH][MD]
    float* Sin   = carry + (size_t)B_ * NCH * MD;
    u16* ax0 = xb;                               // aq (xb dead after G1)
    u16* ax1 = xb + (size_t)NTOK * MD;           // ak

    dim3 blk(256);
    dim3 t32(32, 8);

    cvt_bf16_k<<<(NTOK * DD) / (256 * 8), blk, 0, stream>>>(x, xb, NTOK * DD);
    wtrans_k<<<dim3(16, 32), t32, 0, stream>>>(Wd, wdT, 1024, 512);
    wtrans5_k<<<dim3(16, 16, 5), t32, 0, stream>>>(Wq, Wk, Wv, W0, W1,
        wqT, wkT, wvT, w0T, w1T);
    wtrans_k<<<dim3(32, 16), t32, 0, stream>>>(Wu, wuT, 512, 1024);

    // G1: h = x @ Wd + bd -> hb. K=1024, grid 512
    gemm_bf16_k<0, 1, 1><<<dim3(512, 1, 1), blk, 0, stream>>>(
        xb, xb, xb, wdT, wdT, wdT, bd, bd, bd, hb, hb, hb, 1024, 4, 512);
    // G234 (z-merged): qpre/kpre/v = h @ {Wq,Wk,Wv} + bias -> {b1,b2,VB}
    gemm_bf16_k<0, 1, 1><<<dim3(512, 1, 3), blk, 0, stream>>>(
        hb, hb, hb, wqT, wkT, wvT, bq, bk, bv, b1, b2, VB, 512, 4, 512);
    // LN in-place on b1,b2
    ln2_k<<<dim3(NTOK, 2), blk, 0, stream>>>(b1, b2, qg, qb, kg, kb);
    // G57 (z-merged): {aq,ak} = gelu({q,k} @ W0) -> {ax0,ax1}
    gemm_bf16_k<1, 0, 1><<<dim3(512, 1, 2), blk, 0, stream>>>(
        b1, b2, b2, w0T, w0T, w0T, nullptr, nullptr, nullptr, ax0, ax1, ax1, 512, 4, 512);
    // G68 (z-merged): {retrieved,pred} = {aq,ak} @ W1 -> {b1,b2}
    gemm_bf16_k<0, 0, 1><<<dim3(512, 1, 2), blk, 0, stream>>>(
        ax0, ax1, ax1, w1T, w1T, w1T, nullptr, nullptr, nullptr, b1, b2, b2, 512, 4, 512);
    // surprise coefficient per token
    surprise_k<<<NTOK, blk, 0, stream>>>(b2, VB, lr, coef);
    // chunked scan over inputs = coef * v (VB in-place -> scan local)
    scan1_k<<<(B_ * NCH * (MD / 4)) / 256, blk, 0, stream>>>(VB, coef, ff, carry);
    scan2_k<<<(B_ * MD) / 256, blk, 0, stream>>>(carry, ff, Sin);
    // fin = loc + g^..*Sin + retrieved -> hb (h dead)
    scan3_k<<<(NTOK * (MD / 4)) / 256, blk, 0, stream>>>(VB, Sin, b1, ff, hb);
    // G9: out = fin @ Wu + bu (f32 out). grid 1024
    gemm_bf16_k<0, 1, 0><<<dim3(1024, 1, 1), blk, 0, stream>>>(
        hb, hb, hb, wuT, wuT, wuT, bu, bu, bu, out, out, out, 512, 8, 1024);
}